// Round 1
// baseline (561.363 us; speedup 1.0000x reference)
//
#include <hip/hip_runtime.h>
#include <hip/hip_bf16.h>
#include <math.h>

typedef __hip_bfloat16 bf16;
typedef __attribute__((ext_vector_type(8))) short s8v;   // 8 bf16 = 4 VGPR (MFMA A/B frag)
typedef __attribute__((ext_vector_type(4))) short s4v;   // 4 bf16 = 8B
typedef __attribute__((ext_vector_type(4))) float f4v;   // MFMA C/D frag

// B=256, S=32, D=512, HW=196
#define BB 256
#define SS 32
#define DD 512
#define HWN 196
#define AP 40   // LDS row pitch (bf16): 80 B -> conflict-free b128 frag reads

__device__ __forceinline__ float b2f(bf16 x){ return __bfloat162float(x); }
__device__ __forceinline__ bf16 f2b(float x){ return __float2bfloat16(x); }
__device__ __forceinline__ float us2f(unsigned short u){
    union { unsigned int i; float f; } t; t.i = ((unsigned int)u) << 16; return t.f;
}
// dt: 1 = inputs are bf16, 0 = inputs are fp32 (runtime-uniform)
__device__ __forceinline__ float ldin(int dt, const void* p, size_t i){
    return dt ? b2f(((const bf16*)p)[i]) : ((const float*)p)[i];
}

// ---------------- dtype detector ----------------
__global__ void detect_k(const void* q, int* flag){
    __shared__ int cnt;
    if (threadIdx.x == 0) cnt = 0;
    __syncthreads();
    const unsigned short* u = (const unsigned short*)q;
    unsigned short v = u[threadIdx.x * 4];
    int e = (v >> 7) & 0xFF;
    atomicAdd(&cnt, (e >= 100 && e <= 140) ? 1 : 0);
    __syncthreads();
    if (threadIdx.x == 0) *flag = (cnt > 128) ? 1 : 0;
}

// ---------------- fused weight prep (runtime dt; per-dtype alt pointers) ----------------
struct PJob { const void* s; const void* s_b; const void* s2; const void* s2_b;
              bf16* d; int R, C, ldd, kofs, mode, boff; };
struct PrepP { PJob j[11]; const void* war; const void* bk; float* warf; float* bkf; };

__global__ __launch_bounds__(256) void prep_k(PrepP P, const int* __restrict__ flag){
    const int dt = *flag;
    __shared__ float T[32][33];
    int bx = blockIdx.x;
    int ji = 0;
    #pragma unroll
    for (int i = 0; i < 11; ++i) if (bx >= P.j[i].boff) ji = i;
    PJob jb = P.j[ji];
    const void* src  = dt ? jb.s_b  : jb.s;
    const void* src2 = dt ? jb.s2_b : jb.s2;
    int t = bx - jb.boff;
    int tx = threadIdx.x & 31, ty = threadIdx.x >> 5;
    if (jb.mode == 3){
        for (int i = threadIdx.x; i < DD; i += 256){
            P.warf[i] = ldin(dt, P.war, i);
            P.bkf[i]  = ldin(dt, P.bk, i);
        }
        return;
    }
    int nrt = jb.R >> 5;
    int r0 = (t % nrt) << 5, c0 = (t / nrt) << 5;
    if (jb.mode == 2){
        for (int rr = ty; rr < 32; rr += 8)
            jb.d[(size_t)(r0 + rr) * jb.ldd + jb.kofs + c0 + tx] =
                f2b(ldin(dt, src, (size_t)(r0 + rr) * jb.C + c0 + tx));
        return;
    }
    for (int rr = ty; rr < 32; rr += 8){
        float v = ldin(dt, src, (size_t)(r0 + rr) * jb.C + c0 + tx);
        if (jb.mode == 1) v += ldin(dt, src2, (size_t)(r0 + rr) * jb.C + c0 + tx);
        T[rr][tx] = v;
    }
    __syncthreads();
    for (int rr = ty; rr < 32; rr += 8)
        jb.d[(size_t)(c0 + rr) * jb.ldd + jb.kofs + r0 + tx] = f2b(T[tx][rr]);
}

// ---- block swizzle: 8 c-tiles of one rt within a 64-id window, same XCD (id%8==rt%8) ----
__device__ __forceinline__ void tile_decode(int idb, int swz, int& rt, int& ct){
    if (swz){ int g = idb >> 6, w = idb & 63; rt = g * 8 + (w & 7); ct = w >> 3; }
    else    { ct = idb & 7; rt = idb >> 3; }
}

// ---------------- MFMA GEMM 1: pkT[M,512] = knowT[M,512] @ WkT^T + bk ----------------
// Reads know[b][d][n] DIRECTLY (fp32 or bf16); transpose happens in the staging path:
// each thread owns a 4k x 4n micro-tile (n-quads are 4-aligned and 4|196, so a quad
// never crosses a batch boundary), loads 4 vector rows, transposes in registers,
// writes 4x ds_write_b64 into the AP-padded A tile.
__global__ __launch_bounds__(256) void g1_mfma(const void* __restrict__ know,
                                               const bf16* __restrict__ BT,
                                               const float* __restrict__ bkf,
                                               bf16* __restrict__ C,
                                               int b0, int swz,
                                               const int* __restrict__ flag){
    const int dt = *flag;
    __shared__ __align__(16) bf16 As[128 * AP];
    __shared__ __align__(16) bf16 Bs[64 * AP];
    const int tid = threadIdx.x, lane = tid & 63, wave = tid >> 6;
    const int q = lane >> 4, mr = lane & 15;
    int rt, ct; tile_decode(blockIdx.x, swz, rt, ct);
    const int r0 = rt * 128, c0 = ct * 64;
    // A transpose-staging constants
    const int quad = tid >> 3;            // 0..31 : 4-row (n) group
    const int kg   = tid & 7;             // 0..7  : 4-k group
    const int m    = r0 + quad * 4;       // chunk-local M row (multiple of 4)
    const int bl   = m / HWN;             // chunk-local batch
    const int n    = m - bl * HWN;        // multiple of 4, <= 192
    const size_t abase = ((size_t)(b0 + bl) * DD) * HWN + n;   // element offset at k=0
    f4v acc[2][4];
    #pragma unroll
    for (int t = 0; t < 2; ++t)
        #pragma unroll
        for (int j = 0; j < 4; ++j){ f4v z = {0.f,0.f,0.f,0.f}; acc[t][j] = z; }
    for (int k0 = 0; k0 < DD; k0 += 32){
        // ---- A: load 4x4 (k x n) micro-tile from know, transpose, store bf16 ----
        union { bf16 h[4]; s4v v; } pk_[4];
        if (dt == 0){
            const float* kp = (const float*)know + abase + (size_t)(k0 + kg * 4) * HWN;
            float4 ra = *(const float4*)kp;
            float4 rb = *(const float4*)(kp + HWN);
            float4 rc = *(const float4*)(kp + 2 * HWN);
            float4 rd4 = *(const float4*)(kp + 3 * HWN);
            #pragma unroll
            for (int j = 0; j < 4; ++j){
                pk_[j].h[0] = f2b((&ra.x)[j]);
                pk_[j].h[1] = f2b((&rb.x)[j]);
                pk_[j].h[2] = f2b((&rc.x)[j]);
                pk_[j].h[3] = f2b((&rd4.x)[j]);
            }
        } else {
            const unsigned short* kp = (const unsigned short*)know + abase + (size_t)(k0 + kg * 4) * HWN;
            ushort4 ua = *(const ushort4*)kp;
            ushort4 ub = *(const ushort4*)(kp + HWN);
            ushort4 uc = *(const ushort4*)(kp + 2 * HWN);
            ushort4 ud = *(const ushort4*)(kp + 3 * HWN);
            #pragma unroll
            for (int j = 0; j < 4; ++j){
                ((unsigned short*)&pk_[j].v)[0] = (&ua.x)[j];
                ((unsigned short*)&pk_[j].v)[1] = (&ub.x)[j];
                ((unsigned short*)&pk_[j].v)[2] = (&uc.x)[j];
                ((unsigned short*)&pk_[j].v)[3] = (&ud.x)[j];
            }
        }
        #pragma unroll
        for (int j = 0; j < 4; ++j)
            *(s4v*)&As[(quad * 4 + j) * AP + kg * 4] = pk_[j].v;
        // ---- B staging (bf16, pre-transposed weights) ----
        {
            int col = tid >> 2, ko = (tid & 3) * 8;
            *(float4*)&Bs[col * AP + ko] =
                *(const float4*)(BT + (size_t)(c0 + col) * DD + k0 + ko);
        }
        __syncthreads();
        s8v a0 = *(const s8v*)&As[(wave * 32 + mr) * AP + q * 8];
        s8v a1 = *(const s8v*)&As[(wave * 32 + 16 + mr) * AP + q * 8];
        #pragma unroll
        for (int j = 0; j < 4; ++j){
            s8v b = *(const s8v*)&Bs[(j * 16 + mr) * AP + q * 8];
            acc[0][j] = __builtin_amdgcn_mfma_f32_16x16x32_bf16(a0, b, acc[0][j], 0, 0, 0);
            acc[1][j] = __builtin_amdgcn_mfma_f32_16x16x32_bf16(a1, b, acc[1][j], 0, 0, 0);
        }
        __syncthreads();
    }
    #pragma unroll
    for (int t = 0; t < 2; ++t)
        #pragma unroll
        for (int j = 0; j < 4; ++j)
            #pragma unroll
            for (int i = 0; i < 4; ++i){
                int row = r0 + wave * 32 + t * 16 + q * 4 + i;
                int col = c0 + j * 16 + mr;
                C[(size_t)row * DD + col] = f2b(acc[t][j][i] + bkf[col]);
            }
}

// ---------------- MFMA GEMM 2 (per-batch, K=512, pm folded into B) ----------
__global__ __launch_bounds__(256) void g2_mfma(const bf16* __restrict__ Apk,
                                               const bf16* __restrict__ BT,
                                               const float* __restrict__ pmf,
                                               const float* __restrict__ t3b,
                                               const float* __restrict__ uf,
                                               float* __restrict__ lpart,
                                               int b0, int swz){
    __shared__ __align__(16) bf16 As[128 * AP];
    __shared__ __align__(16) bf16 Bs[64 * AP];
    const int tid = threadIdx.x, lane = tid & 63, wave = tid >> 6;
    const int q = lane >> 4, mr = lane & 15;
    int idb = blockIdx.x, u, ct;
    if (swz){ int g = idb >> 6, w = idb & 63; u = g * 8 + (w & 7); ct = w >> 3; }
    else    { u = idb >> 3; ct = idb & 7; }
    const int bl = u >> 1, rt = u & 1;
    const int b = b0 + bl;
    const int c0 = ct * 64, rbase = rt * 128;
    const float* pmb = pmf + (size_t)b * DD;
    f4v acc[2][4];
    #pragma unroll
    for (int t = 0; t < 2; ++t)
        #pragma unroll
        for (int j = 0; j < 4; ++j){ f4v z = {0.f,0.f,0.f,0.f}; acc[t][j] = z; }
    for (int k0 = 0; k0 < DD; k0 += 32){
        #pragma unroll
        for (int cc = 0; cc < 2; ++cc){
            int c = tid + cc * 256;
            int row = c >> 2, ko = (c & 3) * 8;
            int rl = rbase + row;
            float4 v = {0.f, 0.f, 0.f, 0.f};
            if (rl < HWN)
                v = *(const float4*)(Apk + ((size_t)bl * HWN + rl) * DD + k0 + ko);
            *(float4*)&As[row * AP + ko] = v;
        }
        {
            int col = tid >> 2, ko = (tid & 3) * 8;
            const bf16* wrow = BT + (size_t)(c0 + col) * (2 * DD) + k0 + ko;
            union { bf16 h[8]; float4 f; } w1, w2, be;
            w1.f = *(const float4*)wrow;
            w2.f = *(const float4*)(wrow + DD);
            float4 pA = *(const float4*)(pmb + k0 + ko);
            float4 pB = *(const float4*)(pmb + k0 + ko + 4);
            #pragma unroll
            for (int j = 0; j < 4; ++j){
                be.h[j]     = f2b((&pA.x)[j] * b2f(w1.h[j])     + b2f(w2.h[j]));
                be.h[4 + j] = f2b((&pB.x)[j] * b2f(w1.h[4 + j]) + b2f(w2.h[4 + j]));
            }
            *(float4*)&Bs[col * AP + ko] = be.f;
        }
        __syncthreads();
        s8v a0 = *(const s8v*)&As[(wave * 32 + mr) * AP + q * 8];
        s8v a1 = *(const s8v*)&As[(wave * 32 + 16 + mr) * AP + q * 8];
        #pragma unroll
        for (int j = 0; j < 4; ++j){
            s8v b2 = *(const s8v*)&Bs[(j * 16 + mr) * AP + q * 8];
            acc[0][j] = __builtin_amdgcn_mfma_f32_16x16x32_bf16(a0, b2, acc[0][j], 0, 0, 0);
            acc[1][j] = __builtin_amdgcn_mfma_f32_16x16x32_bf16(a1, b2, acc[1][j], 0, 0, 0);
        }
        __syncthreads();
    }
    float part[2][4] = {};
    #pragma unroll
    for (int t = 0; t < 2; ++t)
        #pragma unroll
        for (int j = 0; j < 4; ++j)
            #pragma unroll
            for (int i = 0; i < 4; ++i){
                int rl = rbase + wave * 32 + t * 16 + q * 4 + i;
                if (rl < HWN){
                    int col = c0 + j * 16 + mr;
                    float hv = acc[t][j][i] + t3b[(size_t)b * DD + col];
                    part[t][i] += fmaxf(hv, 0.f) * uf[(size_t)b * DD + col];
                }
            }
    #pragma unroll
    for (int t = 0; t < 2; ++t)
        #pragma unroll
        for (int i = 0; i < 4; ++i){
            float v = part[t][i];
            v += __shfl_xor(v, 1, 16);
            v += __shfl_xor(v, 2, 16);
            v += __shfl_xor(v, 4, 16);
            v += __shfl_xor(v, 8, 16);
            int rl = rbase + wave * 32 + t * 16 + q * 4 + i;
            if (mr == 0 && rl < HWN)
                lpart[(size_t)ct * (BB * HWN) + (size_t)b * HWN + rl] = v;
        }
}

// ---------------- fast small GEMM: LDS-free, one 16x16 MFMA tile per wave ----------------
// Up to 2 independent jobs co-launched via blockIdx.z (launch-count reduction).
struct SSeg { const void* A; int a_ws, lda, K, koff; };
struct SP {
    SSeg s[2]; int nseg;
    const bf16* BT; int ldb;       // BT[n][k] bf16
    const float* amul;             // optional per-k multiplier on A (seg 0 only)
    const void* bias;              // raw input dtype, may be null
    float* C; int M, N, act;       // act: 0 none, 1 tanh
    void* out2; int o2off;         // optional extra output (input dtype), at o2off
};
struct SPP { SP j[2]; };

__global__ __launch_bounds__(256) void sgemm_k(SPP P, const int* __restrict__ flag){
    const int dt = *flag;
    const SP p = P.j[blockIdx.z];
    const int tid = threadIdx.x, lane = tid & 63, w = tid >> 6;
    const int q = lane >> 4, mr = lane & 15;
    const int n0 = blockIdx.x * 16, m0 = blockIdx.y * 64 + w * 16;
    f4v acc = {0.f,0.f,0.f,0.f};
    for (int sg = 0; sg < p.nseg; ++sg){
        const SSeg s = p.s[sg];
        const float* amul = (sg == 0) ? p.amul : nullptr;
        #pragma unroll 4
        for (int k0 = 0; k0 < s.K; k0 += 32){
            const int kk = k0 + q * 8;
            union { bf16 h[8]; s8v v; } a;
            if (s.a_ws || dt == 0){
                const float* Af = (const float*)s.A + (size_t)(m0 + mr) * s.lda + kk;
                float4 f0 = *(const float4*)Af;
                float4 f1 = *(const float4*)(Af + 4);
                float f[8] = {f0.x, f0.y, f0.z, f0.w, f1.x, f1.y, f1.z, f1.w};
                if (amul){
                    #pragma unroll
                    for (int j = 0; j < 8; ++j) f[j] *= amul[kk + j];
                }
                #pragma unroll
                for (int j = 0; j < 8; ++j) a.h[j] = f2b(f[j]);
            } else {
                a.v = *(const s8v*)((const bf16*)s.A + (size_t)(m0 + mr) * s.lda + kk);
                if (amul){
                    #pragma unroll
                    for (int j = 0; j < 8; ++j) a.h[j] = f2b(b2f(a.h[j]) * amul[kk + j]);
                }
            }
            s8v b = *(const s8v*)(p.BT + (size_t)(n0 + mr) * p.ldb + s.koff + kk);
            acc = __builtin_amdgcn_mfma_f32_16x16x32_bf16(a.v, b, acc, 0, 0, 0);
        }
    }
    #pragma unroll
    for (int i = 0; i < 4; ++i){
        int row = m0 + q * 4 + i, col = n0 + mr;
        float v = acc[i] + (p.bias ? ldin(dt, p.bias, col) : 0.f);
        if (p.act == 1) v = tanhf(v);
        p.C[(size_t)row * p.N + col] = v;
        if (p.out2){
            size_t oi = (size_t)p.o2off + (size_t)row * p.N + col;
            if (dt) ((bf16*)p.out2)[oi] = f2b(v);
            else    ((float*)p.out2)[oi] = v;
        }
    }
}

// ---------------- control attention (+ fused bias_r, + fused d_out write) ----------------
__global__ __launch_bounds__(256) void attn_control_k(const float* __restrict__ cq,
                                                      const void* __restrict__ wac,
                                                      const void* __restrict__ bac,
                                                      const void* __restrict__ words,
                                                      float* __restrict__ control,
                                                      const void* __restrict__ bc2,
                                                      const float* __restrict__ warf,
                                                      const void* __restrict__ bar,
                                                      float* __restrict__ bias_r,
                                                      void* __restrict__ out,
                                                      const int* __restrict__ flag){
    const int dt = *flag;
    const int b = blockIdx.x, tid = threadIdx.x;
    __shared__ float cw[DD];
    __shared__ float lg[SS];
    __shared__ float es[SS];
    __shared__ float red[256];
    for (int d = tid; d < DD; d += 256) cw[d] = cq[(size_t)b*DD + d] * ldin(dt, wac, d);
    __syncthreads();
    int s = tid >> 3, l8 = tid & 7;
    float p = 0.f;
    for (int d = l8; d < DD; d += 8) p += cw[d] * ldin(dt, words, ((size_t)b*SS + s)*DD + d);
    for (int off = 4; off; off >>= 1) p += __shfl_down(p, off, 8);
    if (l8 == 0) lg[s] = p + ldin(dt, bac, 0);
    __syncthreads();
    if (tid == 0){
        float mx = -INFINITY;
        for (int i = 0; i < SS; ++i) mx = fmaxf(mx, lg[i]);
        float sm = 0.f;
        for (int i = 0; i < SS; ++i){ es[i] = expf(lg[i] - mx); sm += es[i]; }
        float inv = 1.f / sm;
        for (int i = 0; i < SS; ++i) es[i] *= inv;
    }
    __syncthreads();
    float vb = 0.f;
    for (int d = tid; d < DD; d += 256){
        float c = 0.f;
        #pragma unroll 8
        for (int s2 = 0; s2 < SS; ++s2) c += es[s2] * ldin(dt, words, ((size_t)b*SS + s2)*DD + d);
        control[(size_t)b*DD + d] = c;
        // first half of output: control (input dtype)
        if (dt) ((bf16*)out)[(size_t)b*DD + d] = f2b(c);
        else    ((float*)out)[(size_t)b*DD + d] = c;
        // fused vbias: bias_r = dot(bc2, control*war) + bar
        vb += ldin(dt, bc2, d) * c * warf[d];
    }
    red[tid] = vb; __syncthreads();
    for (int off = 128; off; off >>= 1){ if (tid < off) red[tid] += red[tid + off]; __syncthreads(); }
    if (tid == 0) bias_r[b] = red[0] + ldin(dt, bar, 0);
}

// ---------------- softmax over HW + read (fused deterministic lpart reduce) ----------------
__global__ __launch_bounds__(256) void softmax_read_k(const float* __restrict__ lpart,
                                                      const float* __restrict__ bias_r,
                                                      const void* __restrict__ know,
                                                      float* __restrict__ readout,
                                                      const int* __restrict__ flag){
    const int dt = *flag;
    const int b = blockIdx.x, tid = threadIdx.x;
    __shared__ float a[HWN];
    __shared__ float red[256];
    float x = -INFINITY;
    if (tid < HWN){
        float sacc = bias_r[b];
        #pragma unroll
        for (int c = 0; c < 8; ++c)
            sacc += lpart[(size_t)c * (BB * HWN) + (size_t)b * HWN + tid];
        x = sacc;
    }
    red[tid] = x; __syncthreads();
    for (int off = 128; off; off >>= 1){ if (tid < off) red[tid] = fmaxf(red[tid], red[tid + off]); __syncthreads(); }
    float mx = red[0]; __syncthreads();
    float e = (tid < HWN) ? expf(x - mx) : 0.f;
    red[tid] = e; __syncthreads();
    for (int off = 128; off; off >>= 1){ if (tid < off) red[tid] += red[tid + off]; __syncthreads(); }
    float inv = 1.f / red[0];
    if (tid < HWN) a[tid] = e * inv;
    __syncthreads();
    for (int d = tid; d < DD; d += 256){
        size_t base = ((size_t)b*DD + d) * HWN;
        float sum = 0.f;
        if (dt){
            const ushort4* k4 = (const ushort4*)((const unsigned short*)know + base);
            #pragma unroll 7
            for (int c = 0; c < HWN/4; ++c){
                ushort4 u4 = k4[c];
                sum += a[4*c+0]*us2f(u4.x) + a[4*c+1]*us2f(u4.y)
                     + a[4*c+2]*us2f(u4.z) + a[4*c+3]*us2f(u4.w);
            }
        } else {
            const float4* k4 = (const float4*)((const float*)know + base);
            #pragma unroll 7
            for (int c = 0; c < HWN/4; ++c){
                float4 f4 = k4[c];
                sum += a[4*c+0]*f4.x + a[4*c+1]*f4.y + a[4*c+2]*f4.z + a[4*c+3]*f4.w;
            }
        }
        readout[(size_t)b*DD + d] = sum;
    }
}

extern "C" void kernel_launch(void* const* d_in, const int* in_sizes, int n_in,
                              void* d_out, int out_size, void* d_ws, size_t ws_size,
                              hipStream_t stream){
    const void* words    = d_in[0];
    const void* question = d_in[1];
    const void* know     = d_in[2];
    const void* control0 = d_in[3];
    const void* memory0  = d_in[4];
    const void* Wsc = d_in[5];   const void* bsc = d_in[6];
    const void* Wp  = d_in[7];   const void* bp  = d_in[8];
    const void* Wcq = d_in[9];   const void* bcq = d_in[10];
    const void* wac = d_in[11];  const void* bac = d_in[12];
    const void* Wm  = d_in[13];  const void* bm  = d_in[14];
    const void* Wk  = d_in[15];  const void* bk  = d_in[16];
    const void* Wc1 = d_in[17];  const void* bc1 = d_in[18];
    const void* Wc2 = d_in[19];  const void* bc2 = d_in[20];
    const void* war = d_in[21];  const void* bar = d_in[22];
    // d_in[23..26] dead: softmax over singleton axis == 1 => attn_mem == memory0
    const void* Wwcat = d_in[27]; const void* bwcat = d_in[28];

    int* flag = (int*)d_ws;
    float* F = ((float*)d_ws) + 16;
    const int NBD = BB * DD;
    float* q_   = F;
    float* pa   = F + 1*NBD;
    float* cq   = F + 2*NBD;
    float* ctrl = F + 3*NBD;
    float* pm   = F + 4*NBD;
    float* t3b  = F + 5*NBD;
    float* u_   = F + 6*NBD;
    float* rd   = F + 7*NBD;
    float* nm   = F + 8*NBD;
    float* bias_r = F + 9*NBD;                  // [B]
    float* warf   = bias_r + BB;                // [D]
    float* bkf    = warf + DD;                  // [D]
    float* lpart  = bkf + DD;                   // [8][B*HW]
    size_t off_f = 16 + 9*(size_t)NBD + BB + 2*DD + 8*(size_t)BB*HWN;
    size_t byte_off = (off_f * 4 + 255) & ~(size_t)255;
    bf16* WB = (bf16*)((char*)d_ws + byte_off);
    bf16* WscT   = WB;                          // [512][1024]
    bf16* WcqT   = WscT  + (size_t)DD*2*DD;     // [512][1024]
    bf16* Wc1T2  = WcqT  + (size_t)DD*2*DD;     // [512][1024]
    bf16* WwcatF = Wc1T2 + (size_t)DD*2*DD;     // [512][1024]
    bf16* WpT    = WwcatF+ (size_t)DD*2*DD;     // [512][512]
    bf16* WmT    = WpT   + (size_t)DD*DD;
    bf16* Wc1t3T = WmT   + (size_t)DD*DD;
    bf16* WkT    = Wc1t3T+ (size_t)DD*DD;
    bf16* Wc2cv  = WkT   + (size_t)DD*DD;
    size_t big_off = (byte_off + ((size_t)DD*2*DD*4 + (size_t)DD*DD*5) * sizeof(bf16) + 255) & ~(size_t)255;

    size_t per_batch = (size_t)HWN * DD * sizeof(bf16);         // pkT only (knowT gone)
    size_t avail = (ws_size > big_off) ? (ws_size - big_off) : 0;
    int CB = (int)(avail / per_batch);
    CB &= ~31;                                                  // multiple of 32
    if (CB > BB) CB = BB;
    if (CB < 32) CB = 32;
    bf16* pkT = (bf16*)((char*)d_ws + big_off);                 // [CB][196][512]

    dim3 blk(256);

    detect_k<<<dim3(1), blk, 0, stream>>>(question, flag);

    // ---- fused weight prep (single launch, runtime dt) ----
    {
        PrepP P; int bo = 0;
        auto J = [&](const void* s, const void* sb, const void* s2, const void* s2b,
                     bf16* d, int R, int C, int ldd, int kofs, int mode, int idx){
            int nb = (mode == 3) ? 1 : ((R >> 5) * (C >> 5));
            P.j[idx] = PJob{ s, sb, s2, s2b, d, R, C, ldd, kofs, mode, bo };
            bo += nb;
        };
        const void* Wc1t3_f = (const void*)((const float*)Wc1 + (size_t)2*DD*DD);
        const void* Wc1t3_b = (const void*)((const bf16*) Wc1 + (size_t)2*DD*DD);
        const void* Ww1_f = (const void*)((const float*)Wwcat + (size_t)DD*DD);
        const void* Ww1_b = (const void*)((const bf16*) Wwcat + (size_t)DD*DD);
        const void* Ww2_f = (const void*)((const float*)Wwcat + (size_t)2*DD*DD);
        const void* Ww2_b = (const void*)((const bf16*) Wwcat + (size_t)2*DD*DD);
        J(Wsc,   Wsc,   nullptr, nullptr, WscT,   2*DD, DD, 2*DD, 0,   0, 0);
        J(Wp,    Wp,    nullptr, nullptr, WpT,    DD,   DD, DD,   0,   0, 1);
        J(Wcq,   Wcq,   nullptr, nullptr, WcqT,   2*DD, DD, 2*DD, 0,   0, 2);
        J(Wm,    Wm,    nullptr, nullptr, WmT,    DD,   DD, DD,   0,   0, 3);
        J(Wc1,   Wc1,   nullptr, nullptr, Wc1T2,  2*DD, DD, 2*DD, 0,   0, 4);
        J(Wc1t3_f, Wc1t3_b, nullptr, nullptr, Wc1t3T, DD, DD, DD, 0,   0, 5);
        J(Wk,    Wk,    nullptr, nullptr, WkT,    DD,   DD, DD,   0,   0, 6);
        J(Wwcat, Wwcat, nullptr, nullptr, WwcatF, DD,   DD, 2*DD, 0,   0, 7);
        J(Ww1_f, Ww1_b, Ww2_f,   Ww2_b,   WwcatF, DD,   DD, 2*DD, 512, 1, 8);
        J(Wc2,   Wc2,   nullptr, nullptr, Wc2cv,  DD,   DD, DD,   0,   2, 9);
        J(nullptr,nullptr,nullptr,nullptr,nullptr,0,    0,  0,    0,   3, 10);
        P.war = war; P.bk = bk; P.warf = warf; P.bkf = bkf;
        prep_k<<<dim3(bo), blk, 0, stream>>>(P, flag);
    }

    SPP P2;
    auto mkjob = [&](SP& p){ p = SP{}; };

    // launch 1: q = tanh(question @ Wsc + bsc)  ||  pm = memory0 @ Wm + bm
    mkjob(P2.j[0]);
    P2.j[0].nseg = 1;
    P2.j[0].s[0] = SSeg{ question, 0, 2*DD, 2*DD, 0 };
    P2.j[0].BT = WscT; P2.j[0].ldb = 2*DD;
    P2.j[0].bias = bsc; P2.j[0].C = q_; P2.j[0].M = BB; P2.j[0].N = DD; P2.j[0].act = 1;
    mkjob(P2.j[1]);
    P2.j[1].nseg = 1;
    P2.j[1].s[0] = SSeg{ memory0, 0, DD, DD, 0 };
    P2.j[1].BT = WmT; P2.j[1].ldb = DD;
    P2.j[1].bias = bm; P2.j[1].C = pm; P2.j[1].M = BB; P2.j[1].N = DD; P2.j[1].act = 0;
    sgemm_k<<<dim3(DD/16, BB/64, 2), blk, 0, stream>>>(P2, flag);

    // launch 2: pa = q @ Wp + bp  ||  t3b = pm @ Wc1[2D:3D] + bc1
    mkjob(P2.j[0]);
    P2.j[0].nseg = 1;
    P2.j[0].s[0] = SSeg{ q_, 1, DD, DD, 0 };
    P2.j[0].BT = WpT; P2.j[0].ldb = DD;
    P2.j[0].bias = bp; P2.j[0].C = pa; P2.j[0].M = BB; P2.j[0].N = DD; P2.j[0].act = 0;
    mkjob(P2.j[1]);
    P2.j[1].nseg = 1;
    P2.j[1].s[0] = SSeg{ pm, 1, DD, DD, 0 };
    P2.j[1].BT = Wc1t3T; P2.j[1].ldb = DD;
    P2.j[1].bias = bc1; P2.j[1].C = t3b; P2.j[1].M = BB; P2.j[1].N = DD; P2.j[1].act = 0;
    sgemm_k<<<dim3(DD/16, BB/64, 2), blk, 0, stream>>>(P2, flag);

    // launch 3: cq = [control0, pa] @ Wcq + bcq
    mkjob(P2.j[0]);
    P2.j[0].nseg = 2;
    P2.j[0].s[0] = SSeg{ control0, 0, DD, DD, 0 };
    P2.j[0].s[1] = SSeg{ pa,       1, DD, DD, 512 };
    P2.j[0].BT = WcqT; P2.j[0].ldb = 2*DD;
    P2.j[0].bias = bcq; P2.j[0].C = cq; P2.j[0].M = BB; P2.j[0].N = DD; P2.j[0].act = 0;
    sgemm_k<<<dim3(DD/16, BB/64, 1), blk, 0, stream>>>(P2, flag);

    // control (+ fused bias_r, + writes first half of d_out)
    attn_control_k<<<dim3(BB), blk, 0, stream>>>(cq, wac, bac, words, ctrl,
                                                 bc2, warf, bar, bias_r, d_out, flag);

    // u[b,e] = sum_d Wc2[e,d] * (ctrl[b,d]*war[d])
    mkjob(P2.j[0]);
    P2.j[0].nseg = 1;
    P2.j[0].s[0] = SSeg{ ctrl, 1, DD, DD, 0 };
    P2.j[0].BT = Wc2cv; P2.j[0].ldb = DD; P2.j[0].amul = warf;
    P2.j[0].C = u_; P2.j[0].M = BB; P2.j[0].N = DD; P2.j[0].act = 0;
    sgemm_k<<<dim3(DD/16, BB/64, 1), blk, 0, stream>>>(P2, flag);

    // chunked MFMA pipeline: G1 (reads know directly, transposes in staging) -> G2
    for (int b0 = 0; b0 < BB; b0 += CB){
        int cb = (b0 + CB <= BB) ? CB : (BB - b0);
        int M = cb * HWN;                           // multiple of 128 (cb mult of 32)
        int nR = M / 128;
        int swz1 = (nR % 8 == 0) ? 1 : 0;           // compact same-XCD c-tile groups
        g1_mfma<<<dim3(8 * nR), blk, 0, stream>>>(know, WkT, bkf, pkT, b0, swz1, flag);
        int nU = cb * 2;                            // (batch, rtile) units
        int swz2 = (nU % 8 == 0) ? 1 : 0;
        g2_mfma<<<dim3(8 * nU), blk, 0, stream>>>(pkT, Wc1T2, pm, t3b, u_, lpart, b0, swz2);
    }

    // softmax + read (fused deterministic lpart reduce)
    softmax_read_k<<<dim3(BB), blk, 0, stream>>>(lpart, bias_r, know, rd, flag);

    // next_mem = [rd, memory0] @ WwcatF^T + bwcat  (writes second half of d_out directly)
    mkjob(P2.j[0]);
    P2.j[0].nseg = 2;
    P2.j[0].s[0] = SSeg{ rd,      1, DD, DD, 0 };
    P2.j[0].s[1] = SSeg{ memory0, 0, DD, DD, 512 };
    P2.j[0].BT = WwcatF; P2.j[0].ldb = 2*DD;
    P2.j[0].bias = bwcat; P2.j[0].C = nm; P2.j[0].M = BB; P2.j[0].N = DD; P2.j[0].act = 0;
    P2.j[0].out2 = d_out; P2.j[0].o2off = NBD;
    sgemm_k<<<dim3(DD/16, BB/64, 1), blk, 0, stream>>>(P2, flag);
}

// Round 2
// 556.833 us; speedup vs baseline: 1.0081x; 1.0081x over previous
//
#include <hip/hip_runtime.h>
#include <hip/hip_bf16.h>
#include <math.h>

typedef __hip_bfloat16 bf16;
typedef __attribute__((ext_vector_type(8))) short s8v;   // 8 bf16 = 4 VGPR (MFMA A/B frag)
typedef __attribute__((ext_vector_type(4))) short s4v;   // 4 bf16 = 8B
typedef __attribute__((ext_vector_type(4))) float f4v;   // MFMA C/D frag

// B=256, S=32, D=512, HW=196
#define BB 256
#define SS 32
#define DD 512
#define HWN 196
#define APW 72  // LDS row pitch (bf16) for BK=64 tiles: 144 B -> 2-way (free) b128 frag reads

__device__ __forceinline__ float b2f(bf16 x){ return __bfloat162float(x); }
__device__ __forceinline__ bf16 f2b(float x){ return __float2bfloat16(x); }
__device__ __forceinline__ float us2f(unsigned short u){
    union { unsigned int i; float f; } t; t.i = ((unsigned int)u) << 16; return t.f;
}
// dt: 1 = inputs are bf16, 0 = inputs are fp32 (runtime-uniform)
__device__ __forceinline__ float ldin(int dt, const void* p, size_t i){
    return dt ? b2f(((const bf16*)p)[i]) : ((const float*)p)[i];
}

// ---------------- dtype detector ----------------
__global__ void detect_k(const void* q, int* flag){
    __shared__ int cnt;
    if (threadIdx.x == 0) cnt = 0;
    __syncthreads();
    const unsigned short* u = (const unsigned short*)q;
    unsigned short v = u[threadIdx.x * 4];
    int e = (v >> 7) & 0xFF;
    atomicAdd(&cnt, (e >= 100 && e <= 140) ? 1 : 0);
    __syncthreads();
    if (threadIdx.x == 0) *flag = (cnt > 128) ? 1 : 0;
}

// ---------------- fused weight prep (runtime dt; per-dtype alt pointers) ----------------
struct PJob { const void* s; const void* s_b; const void* s2; const void* s2_b;
              bf16* d; int R, C, ldd, kofs, mode, boff; };
struct PrepP { PJob j[11]; const void* war; const void* bk; float* warf; float* bkf; };

__global__ __launch_bounds__(256) void prep_k(PrepP P, const int* __restrict__ flag){
    const int dt = *flag;
    __shared__ float T[32][33];
    int bx = blockIdx.x;
    int ji = 0;
    #pragma unroll
    for (int i = 0; i < 11; ++i) if (bx >= P.j[i].boff) ji = i;
    PJob jb = P.j[ji];
    const void* src  = dt ? jb.s_b  : jb.s;
    const void* src2 = dt ? jb.s2_b : jb.s2;
    int t = bx - jb.boff;
    int tx = threadIdx.x & 31, ty = threadIdx.x >> 5;
    if (jb.mode == 3){
        for (int i = threadIdx.x; i < DD; i += 256){
            P.warf[i] = ldin(dt, P.war, i);
            P.bkf[i]  = ldin(dt, P.bk, i);
        }
        return;
    }
    int nrt = jb.R >> 5;
    int r0 = (t % nrt) << 5, c0 = (t / nrt) << 5;
    if (jb.mode == 2){
        for (int rr = ty; rr < 32; rr += 8)
            jb.d[(size_t)(r0 + rr) * jb.ldd + jb.kofs + c0 + tx] =
                f2b(ldin(dt, src, (size_t)(r0 + rr) * jb.C + c0 + tx));
        return;
    }
    for (int rr = ty; rr < 32; rr += 8){
        float v = ldin(dt, src, (size_t)(r0 + rr) * jb.C + c0 + tx);
        if (jb.mode == 1) v += ldin(dt, src2, (size_t)(r0 + rr) * jb.C + c0 + tx);
        T[rr][tx] = v;
    }
    __syncthreads();
    for (int rr = ty; rr < 32; rr += 8)
        jb.d[(size_t)(c0 + rr) * jb.ldd + jb.kofs + r0 + tx] = f2b(T[tx][rr]);
}

// ---------------- MFMA GEMM 1: pkT[M,512] = know^T @ Wk + bk ----------------
// 128x128 C-tile, BK=64: 32 MFMA per wave between barriers (was 8) -> latency-bound fix.
// Reads know[b][d][n] DIRECTLY; transpose in the staging path (4k x 4n reg micro-tiles).
__global__ __launch_bounds__(256) void g1_mfma(const void* __restrict__ know,
                                               const bf16* __restrict__ BT,
                                               const float* __restrict__ bkf,
                                               bf16* __restrict__ C,
                                               int b0, int swz,
                                               const int* __restrict__ flag){
    const int dt = *flag;
    __shared__ __align__(16) bf16 As[128 * APW];
    __shared__ __align__(16) bf16 Bs[128 * APW];
    const int tid = threadIdx.x, lane = tid & 63, wave = tid >> 6;
    const int q = lane >> 4, mr = lane & 15;
    int idb = blockIdx.x, rt, ct;
    if (swz){ int g = idb >> 5, w = idb & 31; rt = g * 8 + (w & 7); ct = w >> 3; }
    else    { rt = idb >> 2; ct = idb & 3; }
    const int r0 = rt * 128, c0 = ct * 128;
    // A transpose-staging constants (4|196 so an aligned n-quad never crosses a batch)
    const int quad = tid >> 3;            // 0..31 : 4-row (n) group
    const int kg   = tid & 7;             // 0..7  : 4-k group within a 32-k half
    const int m    = r0 + quad * 4;       // chunk-local M row (multiple of 4)
    const int bl   = m / HWN;             // chunk-local batch
    const int n    = m - bl * HWN;        // multiple of 4, <= 192
    const size_t abase = ((size_t)(b0 + bl) * DD) * HWN + n;   // element offset at k=0
    f4v acc[2][8];
    #pragma unroll
    for (int t = 0; t < 2; ++t)
        #pragma unroll
        for (int j = 0; j < 8; ++j){ f4v z = {0.f,0.f,0.f,0.f}; acc[t][j] = z; }
    for (int k0 = 0; k0 < DD; k0 += 64){
        // ---- A: two 4x4 (k x n) micro-tiles from know, transpose, store bf16 ----
        #pragma unroll
        for (int h = 0; h < 2; ++h){
            int kb = k0 + h * 32 + kg * 4;
            union { bf16 hh[4]; s4v v; } pk_[4];
            if (dt == 0){
                const float* kp = (const float*)know + abase + (size_t)kb * HWN;
                float4 ra  = *(const float4*)kp;
                float4 rb  = *(const float4*)(kp + HWN);
                float4 rc  = *(const float4*)(kp + 2 * HWN);
                float4 rd4 = *(const float4*)(kp + 3 * HWN);
                #pragma unroll
                for (int j = 0; j < 4; ++j){
                    pk_[j].hh[0] = f2b((&ra.x)[j]);
                    pk_[j].hh[1] = f2b((&rb.x)[j]);
                    pk_[j].hh[2] = f2b((&rc.x)[j]);
                    pk_[j].hh[3] = f2b((&rd4.x)[j]);
                }
            } else {
                const unsigned short* kp = (const unsigned short*)know + abase + (size_t)kb * HWN;
                ushort4 ua = *(const ushort4*)kp;
                ushort4 ub = *(const ushort4*)(kp + HWN);
                ushort4 uc = *(const ushort4*)(kp + 2 * HWN);
                ushort4 ud = *(const ushort4*)(kp + 3 * HWN);
                #pragma unroll
                for (int j = 0; j < 4; ++j){
                    ((unsigned short*)&pk_[j].v)[0] = (&ua.x)[j];
                    ((unsigned short*)&pk_[j].v)[1] = (&ub.x)[j];
                    ((unsigned short*)&pk_[j].v)[2] = (&uc.x)[j];
                    ((unsigned short*)&pk_[j].v)[3] = (&ud.x)[j];
                }
            }
            #pragma unroll
            for (int j = 0; j < 4; ++j)
                *(s4v*)&As[(quad * 4 + j) * APW + h * 32 + kg * 4] = pk_[j].v;
        }
        // ---- B staging (bf16, pre-transposed weights): 128 cols x 64 k ----
        {
            int col = tid >> 1, kb = (tid & 1) * 32;
            const bf16* wp = BT + (size_t)(c0 + col) * DD + k0 + kb;
            bf16* dst = &Bs[col * APW + kb];
            #pragma unroll
            for (int t4 = 0; t4 < 32; t4 += 8)
                *(float4*)(dst + t4) = *(const float4*)(wp + t4);
        }
        __syncthreads();
        #pragma unroll
        for (int h = 0; h < 2; ++h){
            s8v a0 = *(const s8v*)&As[(wave * 32 + mr) * APW + h * 32 + q * 8];
            s8v a1 = *(const s8v*)&As[(wave * 32 + 16 + mr) * APW + h * 32 + q * 8];
            #pragma unroll
            for (int j = 0; j < 8; ++j){
                s8v b = *(const s8v*)&Bs[(j * 16 + mr) * APW + h * 32 + q * 8];
                acc[0][j] = __builtin_amdgcn_mfma_f32_16x16x32_bf16(a0, b, acc[0][j], 0, 0, 0);
                acc[1][j] = __builtin_amdgcn_mfma_f32_16x16x32_bf16(a1, b, acc[1][j], 0, 0, 0);
            }
        }
        __syncthreads();
    }
    #pragma unroll
    for (int t = 0; t < 2; ++t)
        #pragma unroll
        for (int j = 0; j < 8; ++j){
            float bb = bkf[c0 + j * 16 + mr];
            #pragma unroll
            for (int i = 0; i < 4; ++i){
                int row = r0 + wave * 32 + t * 16 + q * 4 + i;
                int col = c0 + j * 16 + mr;
                C[(size_t)row * DD + col] = f2b(acc[t][j][i] + bb);
            }
        }
}

// ---------------- MFMA GEMM 2 (per-batch, K=512, pm folded into B) ----------
// 128x128 C-tile, BK=64. 4 c-tiles -> lpart has 4 slices.
__global__ __launch_bounds__(256) void g2_mfma(const bf16* __restrict__ Apk,
                                               const bf16* __restrict__ BT,
                                               const float* __restrict__ pmf,
                                               const float* __restrict__ t3b,
                                               const float* __restrict__ uf,
                                               float* __restrict__ lpart,
                                               int b0, int swz){
    __shared__ __align__(16) bf16 As[128 * APW];
    __shared__ __align__(16) bf16 Bs[128 * APW];
    const int tid = threadIdx.x, lane = tid & 63, wave = tid >> 6;
    const int q = lane >> 4, mr = lane & 15;
    int idb = blockIdx.x, u, ct;
    if (swz){ int g = idb >> 5, w = idb & 31; u = g * 8 + (w & 7); ct = w >> 3; }
    else    { u = idb >> 2; ct = idb & 3; }
    const int bl = u >> 1, rt = u & 1;
    const int b = b0 + bl;
    const int c0 = ct * 128, rbase = rt * 128;
    const float* pmb = pmf + (size_t)b * DD;
    f4v acc[2][8];
    #pragma unroll
    for (int t = 0; t < 2; ++t)
        #pragma unroll
        for (int j = 0; j < 8; ++j){ f4v z = {0.f,0.f,0.f,0.f}; acc[t][j] = z; }
    for (int k0 = 0; k0 < DD; k0 += 64){
        // ---- A staging: pk rows (bf16), zero-pad rows >= HWN ----
        {
            int row = tid >> 1, kb = (tid & 1) * 32;
            int rl = rbase + row;
            bf16* dst = &As[row * APW + kb];
            if (rl < HWN){
                const bf16* ap = Apk + ((size_t)bl * HWN + rl) * DD + k0 + kb;
                #pragma unroll
                for (int t4 = 0; t4 < 32; t4 += 8)
                    *(float4*)(dst + t4) = *(const float4*)(ap + t4);
            } else {
                float4 z = {0.f,0.f,0.f,0.f};
                #pragma unroll
                for (int t4 = 0; t4 < 32; t4 += 8)
                    *(float4*)(dst + t4) = z;
            }
        }
        // ---- B staging: W_eff[e,d] = pm[b,e]*Wc1[e,d] + Wc1[D+e,d] ----
        {
            int col = tid >> 1, kb = (tid & 1) * 32;
            const bf16* wrow = BT + (size_t)(c0 + col) * (2 * DD) + k0 + kb;
            bf16* dst = &Bs[col * APW + kb];
            #pragma unroll
            for (int t4 = 0; t4 < 32; t4 += 8){
                union { bf16 h[8]; float4 f; } w1, w2, be;
                w1.f = *(const float4*)(wrow + t4);
                w2.f = *(const float4*)(wrow + DD + t4);
                float4 pA = *(const float4*)(pmb + k0 + kb + t4);
                float4 pB = *(const float4*)(pmb + k0 + kb + t4 + 4);
                #pragma unroll
                for (int j = 0; j < 4; ++j){
                    be.h[j]     = f2b((&pA.x)[j] * b2f(w1.h[j])     + b2f(w2.h[j]));
                    be.h[4 + j] = f2b((&pB.x)[j] * b2f(w1.h[4 + j]) + b2f(w2.h[4 + j]));
                }
                *(float4*)(dst + t4) = be.f;
            }
        }
        __syncthreads();
        #pragma unroll
        for (int h = 0; h < 2; ++h){
            s8v a0 = *(const s8v*)&As[(wave * 32 + mr) * APW + h * 32 + q * 8];
            s8v a1 = *(const s8v*)&As[(wave * 32 + 16 + mr) * APW + h * 32 + q * 8];
            #pragma unroll
            for (int j = 0; j < 8; ++j){
                s8v b2 = *(const s8v*)&Bs[(j * 16 + mr) * APW + h * 32 + q * 8];
                acc[0][j] = __builtin_amdgcn_mfma_f32_16x16x32_bf16(a0, b2, acc[0][j], 0, 0, 0);
                acc[1][j] = __builtin_amdgcn_mfma_f32_16x16x32_bf16(a1, b2, acc[1][j], 0, 0, 0);
            }
        }
        __syncthreads();
    }
    float part[2][4] = {};
    #pragma unroll
    for (int t = 0; t < 2; ++t)
        #pragma unroll
        for (int j = 0; j < 8; ++j)
            #pragma unroll
            for (int i = 0; i < 4; ++i){
                int rl = rbase + wave * 32 + t * 16 + q * 4 + i;
                if (rl < HWN){
                    int col = c0 + j * 16 + mr;
                    float hv = acc[t][j][i] + t3b[(size_t)b * DD + col];
                    part[t][i] += fmaxf(hv, 0.f) * uf[(size_t)b * DD + col];
                }
            }
    #pragma unroll
    for (int t = 0; t < 2; ++t)
        #pragma unroll
        for (int i = 0; i < 4; ++i){
            float v = part[t][i];
            v += __shfl_xor(v, 1, 16);
            v += __shfl_xor(v, 2, 16);
            v += __shfl_xor(v, 4, 16);
            v += __shfl_xor(v, 8, 16);
            int rl = rbase + wave * 32 + t * 16 + q * 4 + i;
            if (mr == 0 && rl < HWN)
                lpart[(size_t)ct * (BB * HWN) + (size_t)b * HWN + rl] = v;
        }
}

// ---------------- fast small GEMM: LDS-free, one 16x16 MFMA tile per wave ----------------
// Up to 2 independent jobs co-launched via blockIdx.z (launch-count reduction).
struct SSeg { const void* A; int a_ws, lda, K, koff; };
struct SP {
    SSeg s[2]; int nseg;
    const bf16* BT; int ldb;       // BT[n][k] bf16
    const float* amul;             // optional per-k multiplier on A (seg 0 only)
    const void* bias;              // raw input dtype, may be null
    float* C; int M, N, act;       // act: 0 none, 1 tanh
    void* out2; int o2off;         // optional extra output (input dtype), at o2off
};
struct SPP { SP j[2]; };

__global__ __launch_bounds__(256) void sgemm_k(SPP P, const int* __restrict__ flag){
    const int dt = *flag;
    const SP p = P.j[blockIdx.z];
    const int tid = threadIdx.x, lane = tid & 63, w = tid >> 6;
    const int q = lane >> 4, mr = lane & 15;
    const int n0 = blockIdx.x * 16, m0 = blockIdx.y * 64 + w * 16;
    f4v acc = {0.f,0.f,0.f,0.f};
    for (int sg = 0; sg < p.nseg; ++sg){
        const SSeg s = p.s[sg];
        const float* amul = (sg == 0) ? p.amul : nullptr;
        #pragma unroll 4
        for (int k0 = 0; k0 < s.K; k0 += 32){
            const int kk = k0 + q * 8;
            union { bf16 h[8]; s8v v; } a;
            if (s.a_ws || dt == 0){
                const float* Af = (const float*)s.A + (size_t)(m0 + mr) * s.lda + kk;
                float4 f0 = *(const float4*)Af;
                float4 f1 = *(const float4*)(Af + 4);
                float f[8] = {f0.x, f0.y, f0.z, f0.w, f1.x, f1.y, f1.z, f1.w};
                if (amul){
                    #pragma unroll
                    for (int j = 0; j < 8; ++j) f[j] *= amul[kk + j];
                }
                #pragma unroll
                for (int j = 0; j < 8; ++j) a.h[j] = f2b(f[j]);
            } else {
                a.v = *(const s8v*)((const bf16*)s.A + (size_t)(m0 + mr) * s.lda + kk);
                if (amul){
                    #pragma unroll
                    for (int j = 0; j < 8; ++j) a.h[j] = f2b(b2f(a.h[j]) * amul[kk + j]);
                }
            }
            s8v b = *(const s8v*)(p.BT + (size_t)(n0 + mr) * p.ldb + s.koff + kk);
            acc = __builtin_amdgcn_mfma_f32_16x16x32_bf16(a.v, b, acc, 0, 0, 0);
        }
    }
    #pragma unroll
    for (int i = 0; i < 4; ++i){
        int row = m0 + q * 4 + i, col = n0 + mr;
        float v = acc[i] + (p.bias ? ldin(dt, p.bias, col) : 0.f);
        if (p.act == 1) v = tanhf(v);
        p.C[(size_t)row * p.N + col] = v;
        if (p.out2){
            size_t oi = (size_t)p.o2off + (size_t)row * p.N + col;
            if (dt) ((bf16*)p.out2)[oi] = f2b(v);
            else    ((float*)p.out2)[oi] = v;
        }
    }
}

// ---------------- control attention (+ fused bias_r, + fused d_out write) ----------------
__global__ __launch_bounds__(256) void attn_control_k(const float* __restrict__ cq,
                                                      const void* __restrict__ wac,
                                                      const void* __restrict__ bac,
                                                      const void* __restrict__ words,
                                                      float* __restrict__ control,
                                                      const void* __restrict__ bc2,
                                                      const float* __restrict__ warf,
                                                      const void* __restrict__ bar,
                                                      float* __restrict__ bias_r,
                                                      void* __restrict__ out,
                                                      const int* __restrict__ flag){
    const int dt = *flag;
    const int b = blockIdx.x, tid = threadIdx.x;
    __shared__ float cw[DD];
    __shared__ float lg[SS];
    __shared__ float es[SS];
    __shared__ float red[256];
    for (int d = tid; d < DD; d += 256) cw[d] = cq[(size_t)b*DD + d] * ldin(dt, wac, d);
    __syncthreads();
    int s = tid >> 3, l8 = tid & 7;
    float p = 0.f;
    for (int d = l8; d < DD; d += 8) p += cw[d] * ldin(dt, words, ((size_t)b*SS + s)*DD + d);
    for (int off = 4; off; off >>= 1) p += __shfl_down(p, off, 8);
    if (l8 == 0) lg[s] = p + ldin(dt, bac, 0);
    __syncthreads();
    if (tid == 0){
        float mx = -INFINITY;
        for (int i = 0; i < SS; ++i) mx = fmaxf(mx, lg[i]);
        float sm = 0.f;
        for (int i = 0; i < SS; ++i){ es[i] = expf(lg[i] - mx); sm += es[i]; }
        float inv = 1.f / sm;
        for (int i = 0; i < SS; ++i) es[i] *= inv;
    }
    __syncthreads();
    float vb = 0.f;
    for (int d = tid; d < DD; d += 256){
        float c = 0.f;
        #pragma unroll 8
        for (int s2 = 0; s2 < SS; ++s2) c += es[s2] * ldin(dt, words, ((size_t)b*SS + s2)*DD + d);
        control[(size_t)b*DD + d] = c;
        // first half of output: control (input dtype)
        if (dt) ((bf16*)out)[(size_t)b*DD + d] = f2b(c);
        else    ((float*)out)[(size_t)b*DD + d] = c;
        // fused vbias: bias_r = dot(bc2, control*war) + bar
        vb += ldin(dt, bc2, d) * c * warf[d];
    }
    red[tid] = vb; __syncthreads();
    for (int off = 128; off; off >>= 1){ if (tid < off) red[tid] += red[tid + off]; __syncthreads(); }
    if (tid == 0) bias_r[b] = red[0] + ldin(dt, bar, 0);
}

// ---------------- softmax over HW + read (fused deterministic lpart reduce, 4 slices) ----
__global__ __launch_bounds__(256) void softmax_read_k(const float* __restrict__ lpart,
                                                      const float* __restrict__ bias_r,
                                                      const void* __restrict__ know,
                                                      float* __restrict__ readout,
                                                      const int* __restrict__ flag){
    const int dt = *flag;
    const int b = blockIdx.x, tid = threadIdx.x;
    __shared__ float a[HWN];
    __shared__ float red[256];
    float x = -INFINITY;
    if (tid < HWN){
        float sacc = bias_r[b];
        #pragma unroll
        for (int c = 0; c < 4; ++c)
            sacc += lpart[(size_t)c * (BB * HWN) + (size_t)b * HWN + tid];
        x = sacc;
    }
    red[tid] = x; __syncthreads();
    for (int off = 128; off; off >>= 1){ if (tid < off) red[tid] = fmaxf(red[tid], red[tid + off]); __syncthreads(); }
    float mx = red[0]; __syncthreads();
    float e = (tid < HWN) ? expf(x - mx) : 0.f;
    red[tid] = e; __syncthreads();
    for (int off = 128; off; off >>= 1){ if (tid < off) red[tid] += red[tid + off]; __syncthreads(); }
    float inv = 1.f / red[0];
    if (tid < HWN) a[tid] = e * inv;
    __syncthreads();
    for (int d = tid; d < DD; d += 256){
        size_t base = ((size_t)b*DD + d) * HWN;
        float sum = 0.f;
        if (dt){
            const ushort4* k4 = (const ushort4*)((const unsigned short*)know + base);
            #pragma unroll 7
            for (int c = 0; c < HWN/4; ++c){
                ushort4 u4 = k4[c];
                sum += a[4*c+0]*us2f(u4.x) + a[4*c+1]*us2f(u4.y)
                     + a[4*c+2]*us2f(u4.z) + a[4*c+3]*us2f(u4.w);
            }
        } else {
            const float4* k4 = (const float4*)((const float*)know + base);
            #pragma unroll 7
            for (int c = 0; c < HWN/4; ++c){
                float4 f4 = k4[c];
                sum += a[4*c+0]*f4.x + a[4*c+1]*f4.y + a[4*c+2]*f4.z + a[4*c+3]*f4.w;
            }
        }
        readout[(size_t)b*DD + d] = sum;
    }
}

extern "C" void kernel_launch(void* const* d_in, const int* in_sizes, int n_in,
                              void* d_out, int out_size, void* d_ws, size_t ws_size,
                              hipStream_t stream){
    const void* words    = d_in[0];
    const void* question = d_in[1];
    const void* know     = d_in[2];
    const void* control0 = d_in[3];
    const void* memory0  = d_in[4];
    const void* Wsc = d_in[5];   const void* bsc = d_in[6];
    const void* Wp  = d_in[7];   const void* bp  = d_in[8];
    const void* Wcq = d_in[9];   const void* bcq = d_in[10];
    const void* wac = d_in[11];  const void* bac = d_in[12];
    const void* Wm  = d_in[13];  const void* bm  = d_in[14];
    const void* Wk  = d_in[15];  const void* bk  = d_in[16];
    const void* Wc1 = d_in[17];  const void* bc1 = d_in[18];
    const void* Wc2 = d_in[19];  const void* bc2 = d_in[20];
    const void* war = d_in[21];  const void* bar = d_in[22];
    // d_in[23..26] dead: softmax over singleton axis == 1 => attn_mem == memory0
    const void* Wwcat = d_in[27]; const void* bwcat = d_in[28];

    int* flag = (int*)d_ws;
    float* F = ((float*)d_ws) + 16;
    const int NBD = BB * DD;
    float* q_   = F;
    float* pa   = F + 1*NBD;
    float* cq   = F + 2*NBD;
    float* ctrl = F + 3*NBD;
    float* pm   = F + 4*NBD;
    float* t3b  = F + 5*NBD;
    float* u_   = F + 6*NBD;
    float* rd   = F + 7*NBD;
    float* nm   = F + 8*NBD;
    float* bias_r = F + 9*NBD;                  // [B]
    float* warf   = bias_r + BB;                // [D]
    float* bkf    = warf + DD;                  // [D]
    float* lpart  = bkf + DD;                   // [4][B*HW] (alloc 8 for headroom)
    size_t off_f = 16 + 9*(size_t)NBD + BB + 2*DD + 8*(size_t)BB*HWN;
    size_t byte_off = (off_f * 4 + 255) & ~(size_t)255;
    bf16* WB = (bf16*)((char*)d_ws + byte_off);
    bf16* WscT   = WB;                          // [512][1024]
    bf16* WcqT   = WscT  + (size_t)DD*2*DD;     // [512][1024]
    bf16* Wc1T2  = WcqT  + (size_t)DD*2*DD;     // [512][1024]
    bf16* WwcatF = Wc1T2 + (size_t)DD*2*DD;     // [512][1024]
    bf16* WpT    = WwcatF+ (size_t)DD*2*DD;     // [512][512]
    bf16* WmT    = WpT   + (size_t)DD*DD;
    bf16* Wc1t3T = WmT   + (size_t)DD*DD;
    bf16* WkT    = Wc1t3T+ (size_t)DD*DD;
    bf16* Wc2cv  = WkT   + (size_t)DD*DD;
    size_t big_off = (byte_off + ((size_t)DD*2*DD*4 + (size_t)DD*DD*5) * sizeof(bf16) + 255) & ~(size_t)255;

    size_t per_batch = (size_t)HWN * DD * sizeof(bf16);         // pkT only
    size_t avail = (ws_size > big_off) ? (ws_size - big_off) : 0;
    int CB = (int)(avail / per_batch);
    CB &= ~31;                                                  // multiple of 32
    if (CB > BB) CB = BB;
    if (CB < 32) CB = 32;
    bf16* pkT = (bf16*)((char*)d_ws + big_off);                 // [CB][196][512]

    dim3 blk(256);

    detect_k<<<dim3(1), blk, 0, stream>>>(question, flag);

    // ---- fused weight prep (single launch, runtime dt) ----
    {
        PrepP P; int bo = 0;
        auto J = [&](const void* s, const void* sb, const void* s2, const void* s2b,
                     bf16* d, int R, int C, int ldd, int kofs, int mode, int idx){
            int nb = (mode == 3) ? 1 : ((R >> 5) * (C >> 5));
            P.j[idx] = PJob{ s, sb, s2, s2b, d, R, C, ldd, kofs, mode, bo };
            bo += nb;
        };
        const void* Wc1t3_f = (const void*)((const float*)Wc1 + (size_t)2*DD*DD);
        const void* Wc1t3_b = (const void*)((const bf16*) Wc1 + (size_t)2*DD*DD);
        const void* Ww1_f = (const void*)((const float*)Wwcat + (size_t)DD*DD);
        const void* Ww1_b = (const void*)((const bf16*) Wwcat + (size_t)DD*DD);
        const void* Ww2_f = (const void*)((const float*)Wwcat + (size_t)2*DD*DD);
        const void* Ww2_b = (const void*)((const bf16*) Wwcat + (size_t)2*DD*DD);
        J(Wsc,   Wsc,   nullptr, nullptr, WscT,   2*DD, DD, 2*DD, 0,   0, 0);
        J(Wp,    Wp,    nullptr, nullptr, WpT,    DD,   DD, DD,   0,   0, 1);
        J(Wcq,   Wcq,   nullptr, nullptr, WcqT,   2*DD, DD, 2*DD, 0,   0, 2);
        J(Wm,    Wm,    nullptr, nullptr, WmT,    DD,   DD, DD,   0,   0, 3);
        J(Wc1,   Wc1,   nullptr, nullptr, Wc1T2,  2*DD, DD, 2*DD, 0,   0, 4);
        J(Wc1t3_f, Wc1t3_b, nullptr, nullptr, Wc1t3T, DD, DD, DD, 0,   0, 5);
        J(Wk,    Wk,    nullptr, nullptr, WkT,    DD,   DD, DD,   0,   0, 6);
        J(Wwcat, Wwcat, nullptr, nullptr, WwcatF, DD,   DD, 2*DD, 0,   0, 7);
        J(Ww1_f, Ww1_b, Ww2_f,   Ww2_b,   WwcatF, DD,   DD, 2*DD, 512, 1, 8);
        J(Wc2,   Wc2,   nullptr, nullptr, Wc2cv,  DD,   DD, DD,   0,   2, 9);
        J(nullptr,nullptr,nullptr,nullptr,nullptr,0,    0,  0,    0,   3, 10);
        P.war = war; P.bk = bk; P.warf = warf; P.bkf = bkf;
        prep_k<<<dim3(bo), blk, 0, stream>>>(P, flag);
    }

    SPP P2;
    auto mkjob = [&](SP& p){ p = SP{}; };

    // launch 1: q = tanh(question @ Wsc + bsc)  ||  pm = memory0 @ Wm + bm
    mkjob(P2.j[0]);
    P2.j[0].nseg = 1;
    P2.j[0].s[0] = SSeg{ question, 0, 2*DD, 2*DD, 0 };
    P2.j[0].BT = WscT; P2.j[0].ldb = 2*DD;
    P2.j[0].bias = bsc; P2.j[0].C = q_; P2.j[0].M = BB; P2.j[0].N = DD; P2.j[0].act = 1;
    mkjob(P2.j[1]);
    P2.j[1].nseg = 1;
    P2.j[1].s[0] = SSeg{ memory0, 0, DD, DD, 0 };
    P2.j[1].BT = WmT; P2.j[1].ldb = DD;
    P2.j[1].bias = bm; P2.j[1].C = pm; P2.j[1].M = BB; P2.j[1].N = DD; P2.j[1].act = 0;
    sgemm_k<<<dim3(DD/16, BB/64, 2), blk, 0, stream>>>(P2, flag);

    // launch 2: pa = q @ Wp + bp  ||  t3b = pm @ Wc1[2D:3D] + bc1
    mkjob(P2.j[0]);
    P2.j[0].nseg = 1;
    P2.j[0].s[0] = SSeg{ q_, 1, DD, DD, 0 };
    P2.j[0].BT = WpT; P2.j[0].ldb = DD;
    P2.j[0].bias = bp; P2.j[0].C = pa; P2.j[0].M = BB; P2.j[0].N = DD; P2.j[0].act = 0;
    mkjob(P2.j[1]);
    P2.j[1].nseg = 1;
    P2.j[1].s[0] = SSeg{ pm, 1, DD, DD, 0 };
    P2.j[1].BT = Wc1t3T; P2.j[1].ldb = DD;
    P2.j[1].bias = bc1; P2.j[1].C = t3b; P2.j[1].M = BB; P2.j[1].N = DD; P2.j[1].act = 0;
    sgemm_k<<<dim3(DD/16, BB/64, 2), blk, 0, stream>>>(P2, flag);

    // launch 3: cq = [control0, pa] @ Wcq + bcq
    mkjob(P2.j[0]);
    P2.j[0].nseg = 2;
    P2.j[0].s[0] = SSeg{ control0, 0, DD, DD, 0 };
    P2.j[0].s[1] = SSeg{ pa,       1, DD, DD, 512 };
    P2.j[0].BT = WcqT; P2.j[0].ldb = 2*DD;
    P2.j[0].bias = bcq; P2.j[0].C = cq; P2.j[0].M = BB; P2.j[0].N = DD; P2.j[0].act = 0;
    sgemm_k<<<dim3(DD/16, BB/64, 1), blk, 0, stream>>>(P2, flag);

    // control (+ fused bias_r, + writes first half of d_out)
    attn_control_k<<<dim3(BB), blk, 0, stream>>>(cq, wac, bac, words, ctrl,
                                                 bc2, warf, bar, bias_r, d_out, flag);

    // u[b,e] = sum_d Wc2[e,d] * (ctrl[b,d]*war[d])
    mkjob(P2.j[0]);
    P2.j[0].nseg = 1;
    P2.j[0].s[0] = SSeg{ ctrl, 1, DD, DD, 0 };
    P2.j[0].BT = Wc2cv; P2.j[0].ldb = DD; P2.j[0].amul = warf;
    P2.j[0].C = u_; P2.j[0].M = BB; P2.j[0].N = DD; P2.j[0].act = 0;
    sgemm_k<<<dim3(DD/16, BB/64, 1), blk, 0, stream>>>(P2, flag);

    // chunked MFMA pipeline: G1 (reads know directly, transposes in staging) -> G2
    for (int b0 = 0; b0 < BB; b0 += CB){
        int cb = (b0 + CB <= BB) ? CB : (BB - b0);
        int M = cb * HWN;                           // multiple of 128 (cb mult of 32)
        int nR = M / 128;
        int swz1 = (nR % 8 == 0) ? 1 : 0;           // compact same-XCD c-tile groups
        g1_mfma<<<dim3(4 * nR), blk, 0, stream>>>(know, WkT, bkf, pkT, b0, swz1, flag);
        int nU = cb * 2;                            // (batch, rtile) units
        int swz2 = (nU % 8 == 0) ? 1 : 0;
        g2_mfma<<<dim3(4 * nU), blk, 0, stream>>>(pkT, Wc1T2, pm, t3b, u_, lpart, b0, swz2);
    }

    // softmax + read (fused deterministic lpart reduce)
    softmax_read_k<<<dim3(BB), blk, 0, stream>>>(lpart, bias_r, know, rd, flag);

    // next_mem = [rd, memory0] @ WwcatF^T + bwcat  (writes second half of d_out directly)
    mkjob(P2.j[0]);
    P2.j[0].nseg = 2;
    P2.j[0].s[0] = SSeg{ rd,      1, DD, DD, 0 };
    P2.j[0].s[1] = SSeg{ memory0, 0, DD, DD, 512 };
    P2.j[0].BT = WwcatF; P2.j[0].ldb = 2*DD;
    P2.j[0].bias = bwcat; P2.j[0].C = nm; P2.j[0].M = BB; P2.j[0].N = DD; P2.j[0].act = 0;
    P2.j[0].out2 = d_out; P2.j[0].o2off = NBD;
    sgemm_k<<<dim3(DD/16, BB/64, 1), blk, 0, stream>>>(P2, flag);
}